// Round 10
// baseline (213.889 us; speedup 1.0000x reference)
//
#include <hip/hip_runtime.h>
#include <hip/hip_bf16.h>
#include <stdint.h>
#include <stddef.h>

// MMD via single signed 2N x 2N RBF gram, lower triangle only.
// Round 17: ZERO-SYNC kernel. r13-r16 showed slice time ~7400 cyc vs ~2200
// pipe demand: the per-slice barrier convoys the 4 waves into same-phase
// lockstep (ds/MFMA/exp2 phases each serialize on their pipe). Fix: drop
// LDS, staging, and ALL barriers — B-fragments load directly from L2-hot
// Zf8 (4 MB; 4x read amplification = ~1 GB L2 traffic, well under the
// 34.5 TB/s ceiling at target times). Waves free-run; phases drift.
// Balance: row-pair blocks split into two equal half-blocks ->
// grid = 64 pairs x 16 strips x 2 halves = 2048 identical blocks.
// Regs: af[2][2]=32 + acc[2][4]=32 AGPR + transients ~48 => ~112 < 128 cap
// at __launch_bounds__(256,4). No swizzle anywhere (no LDS).

#define N_PTS   8192
#define DIM     256
#define TWO_N   16384

typedef __attribute__((ext_vector_type(4))) float f32x4;
typedef __attribute__((ext_vector_type(4))) int   i32x4;
typedef __attribute__((ext_vector_type(8))) int   i32x8;

// ---------------------------------------------------------------------------
// Prep: fp32 -> fp8 e4m3 (row-major) + c2-scaled fp32 row norms; zero partials.
// n2[row] = c2 * |z_row|^2, c2 = -log2e/sigma (epilogue adds directly).
// ---------------------------------------------------------------------------
__global__ __launch_bounds__(256) void mmd_prep(const float* __restrict__ X,
                                                const float* __restrict__ Y,
                                                const int* __restrict__ sigmap,
                                                unsigned char* __restrict__ Zf8,
                                                float* __restrict__ n2,
                                                float* __restrict__ part) {
    if (blockIdx.x == 0 && threadIdx.x < 64) part[threadIdx.x] = 0.0f;

    const int wave = threadIdx.x >> 6;
    const int lane = threadIdx.x & 63;
    const int row  = blockIdx.x * 4 + wave;          // 0 .. TWO_N-1

    const float* src = (row < N_PTS) ? (X + (size_t)row * DIM)
                                     : (Y + (size_t)(row - N_PTS) * DIM);
    float4 v = ((const float4*)src)[lane];           // 64 lanes x 4 = 256

    float s = v.x * v.x + v.y * v.y + v.z * v.z + v.w * v.w;
#pragma unroll
    for (int off = 32; off; off >>= 1) s += __shfl_down(s, off, 64);
    if (lane == 0) {
        const float c2 = -1.4426950408889634f / (float)(*sigmap);
        n2[row] = c2 * s;
    }

    const int p01 = __builtin_amdgcn_cvt_pk_fp8_f32(v.x, v.y, 0, false);
    const int p23 = __builtin_amdgcn_cvt_pk_fp8_f32(v.z, v.w, 0, false);
    const unsigned int pk = ((unsigned)p01 & 0xffffu) | ((unsigned)p23 << 16);
    *(unsigned int*)(Zf8 + (size_t)row * DIM + (size_t)lane * 4) = pk;
}

// ---------------------------------------------------------------------------
// Main. grid = 2048: bid = p*32 + cc*2 + hb. Row pair {p, 127-p}; slice list
// (panel r0 tiles then panel r1 tiles; 2 col-halves each) split at nS/2
// between the hb=0 and hb=1 half-blocks (equal ±1). 4 waves in 4x1; wave
// owns rows rowT*128 + wave*32 .. +32. Per slice (64 cols x K=256):
// 16 global_load_dwordx4 pairs (B-frags, L2-hot) -> 16 MFMA 16x16x128
// MX-fp8 -> epilogue. No LDS, no __syncthreads, no staging.
// ---------------------------------------------------------------------------
__global__ __launch_bounds__(256, 4) void mmd_main(const unsigned char* __restrict__ Zf8,
                                                   const float* __restrict__ n2,
                                                   const int* __restrict__ sigmap,
                                                   float* __restrict__ part) {
    const int bid = (int)blockIdx.x;
    const int p   = bid >> 5;        // 0..63
    const int cc  = (bid >> 1) & 15; // 0..15
    const int hb  = bid & 1;         // half-block
    const int r0  = p;               // row tile 0..63
    const int r1  = 127 - p;         // row tile 64..127

    const int nT0 = (cc <= r0) ? (((r0 - cc) >> 4) + 1) : 0;
    const int nT1 = ((r1 - cc) >> 4) + 1;
    const int nS0 = nT0 * 2;
    const int nS  = nS0 + nT1 * 2;
    const int sBeg = hb ? (nS >> 1) : 0;
    const int sEnd = hb ? nS : (nS >> 1);

    const int t    = threadIdx.x;
    const int wave = t >> 6;         // 0..3: 32-row group
    const int lane = t & 63;
    const int g    = lane >> 4;      // k-quad
    const int ml   = lane & 15;

    const float m2 = 2.8853900817779268f / (float)(*sigmap);   // 2*log2e/sigma
    const int   SC = 0x7f7f7f7f;     // E8M0 unit scales (2^0)

    // ---- A-panel registers (reloaded at panel switch, <=2x per block) ----
    i32x8 af[2][2];
    float a_i[2][4];
    auto loadA = [&](int rowTile) {
        const int rowBase = rowTile * 128;
#pragma unroll
        for (int mt = 0; mt < 2; ++mt) {
            const unsigned char* rp =
                Zf8 + (size_t)(rowBase + wave * 32 + mt * 16 + ml) * 256 + g * 32;
#pragma unroll
            for (int kc = 0; kc < 2; ++kc) {
                union { i32x4 h[2]; i32x8 v; } u;
                u.h[0] = *(const i32x4*)(rp + kc * 128);
                u.h[1] = *(const i32x4*)(rp + kc * 128 + 16);
                af[mt][kc] = u.v;
            }
        }
#pragma unroll
        for (int mt = 0; mt < 2; ++mt)
#pragma unroll
            for (int rr = 0; rr < 4; ++rr)
                a_i[mt][rr] = n2[rowBase + wave * 32 + mt * 16 + g * 4 + rr];
    };

    // slice s -> (rowTile, bc, h)
    auto sliceCol = [&](int s, int& rowT, int& bc, int& h) {
        int si;
        if (s < nS0) { rowT = r0; si = s; }
        else         { rowT = r1; si = s - nS0; }
        bc = cc + (si >> 1) * 16;
        h  = si & 1;
    };

    int rT0, bc0, h0;
    sliceCol(sBeg, rT0, bc0, h0);
    loadA(rT0);
    int curRow = rT0;

    const f32x4 zacc = {0.0f, 0.0f, 0.0f, 0.0f};
    const int laneB = ml * 256 + g * 32;   // lane offset within a col-slice

    float block_acc = 0.0f;

    for (int s = sBeg; s < sEnd; ++s) {
        int rowT, bc, h;
        sliceCol(s, rowT, bc, h);
        if (rowT != curRow) { loadA(rowT); curRow = rowT; }
        const int colBase = bc * 128 + h * 64;

        // per-slice multiplicative column factors
        float eb[4];
#pragma unroll
        for (int nt = 0; nt < 4; ++nt)
            eb[nt] = __builtin_amdgcn_exp2f(n2[colBase + nt * 16 + ml]);

        // B-fragments straight from L2-hot Zf8 (no LDS round trip)
        const unsigned char* sp = Zf8 + (size_t)colBase * 256 + laneB;

        f32x4 acc[2][4];
#pragma unroll
        for (int nt = 0; nt < 4; ++nt) {
#pragma unroll
            for (int kc = 0; kc < 2; ++kc) {
                union { i32x4 hh[2]; i32x8 v; } u;
                u.hh[0] = *(const i32x4*)(sp + nt * 4096 + kc * 128);
                u.hh[1] = *(const i32x4*)(sp + nt * 4096 + kc * 128 + 16);
                const i32x8 bf = u.v;
#pragma unroll
                for (int mt = 0; mt < 2; ++mt)
                    acc[mt][nt] = __builtin_amdgcn_mfma_scale_f32_16x16x128_f8f6f4(
                        af[mt][kc], bf, (kc == 0) ? zacc : acc[mt][nt],
                        0, 0, 0, SC, 0, SC);
            }
        }

        // ---- epilogue for this slice ----
        float ts0 = 0.0f, ts1 = 0.0f, ts2 = 0.0f, ts3 = 0.0f;
#pragma unroll
        for (int mt = 0; mt < 2; ++mt)
#pragma unroll
            for (int nt = 0; nt < 4; ++nt) {
                const float e = eb[nt];
                ts0 = fmaf(__builtin_amdgcn_exp2f(fmaf(acc[mt][nt][0], m2, a_i[mt][0])), e, ts0);
                ts1 = fmaf(__builtin_amdgcn_exp2f(fmaf(acc[mt][nt][1], m2, a_i[mt][1])), e, ts1);
                ts2 = fmaf(__builtin_amdgcn_exp2f(fmaf(acc[mt][nt][2], m2, a_i[mt][2])), e, ts2);
                ts3 = fmaf(__builtin_amdgcn_exp2f(fmaf(acc[mt][nt][3], m2, a_i[mt][3])), e, ts3);
            }
        const float tsum = (ts0 + ts1) + (ts2 + ts3);

        const float sgn = ((bc < 64) == (rowT < 64)) ? 1.0f : -1.0f;
        const float w   = (bc == rowT) ? sgn : 2.0f * sgn;   // symmetry weight
        block_acc = fmaf(w, tsum, block_acc);
    }

    // ---- wave reduction + per-wave hashed atomic (no LDS, no barrier) ----
    float s = block_acc;
#pragma unroll
    for (int off = 32; off; off >>= 1) s += __shfl_down(s, off, 64);
    if (lane == 0)
        atomicAdd(part + (bid & 63), s);
}

// ---------------------------------------------------------------------------
// Finish: reduce 64 partials, scale, write scalar output.
// ---------------------------------------------------------------------------
__global__ __launch_bounds__(64) void mmd_finish(const float* __restrict__ part,
                                                 float* __restrict__ out) {
    const int lane = threadIdx.x & 63;
    float s = part[lane];
#pragma unroll
    for (int off = 32; off; off >>= 1) s += __shfl_down(s, off, 64);
    if (lane == 0) out[0] = s * (1.0f / 67108864.0f);
}

// ---------------------------------------------------------------------------
extern "C" void kernel_launch(void* const* d_in, const int* in_sizes, int n_in,
                              void* d_out, int out_size, void* d_ws, size_t ws_size,
                              hipStream_t stream) {
    const float* X      = (const float*)d_in[0];
    const float* Y      = (const float*)d_in[1];
    const int*   sigmap = (const int*)d_in[2];
    float*       out    = (float*)d_out;

    unsigned char* Zf8  = (unsigned char*)d_ws;                       // 4 MB
    float*         n2   = (float*)((char*)d_ws + (size_t)TWO_N * DIM);
    float*         part = n2 + TWO_N;                                 // 64 floats

    mmd_prep<<<TWO_N / 4, 256, 0, stream>>>(X, Y, sigmap, Zf8, n2, part);
    mmd_main<<<64 * 16 * 2, 256, 0, stream>>>(Zf8, n2, sigmap, part);
    mmd_finish<<<1, 64, 0, stream>>>(part, out);
}

// Round 11
// 123.165 us; speedup vs baseline: 1.7366x; 1.7366x over previous
//
#include <hip/hip_runtime.h>
#include <hip/hip_bf16.h>
#include <stdint.h>
#include <stddef.h>

// MMD via single signed 2N x 2N RBF gram, lower triangle only.
// Round 18: r15 main loop VERBATIM (best: 52.4 us) + finish kernel FUSED
// into mmd_main via last-block-done pattern (2 launches instead of 3).
// Evidence: dur_us - main_dur is a constant ~58-61 us across ALL rounds
// -> fixed prep+finish+launch overhead comparable to the whole remaining
// main-loop headroom. This round isolates the per-launch component.
// r17 lesson: zero-sync L2-direct is latency-bound (MfmaUtil 8.7) — the
// global_load_lds + dbuf + barrier pipeline is what hides memory latency.

#define N_PTS   8192
#define DIM     256
#define TWO_N   16384

#define AS1 __attribute__((address_space(1)))
#define AS3 __attribute__((address_space(3)))

typedef __attribute__((ext_vector_type(4))) float f32x4;
typedef __attribute__((ext_vector_type(4))) int   i32x4;
typedef __attribute__((ext_vector_type(8))) int   i32x8;

// ---------------------------------------------------------------------------
// Prep: fp32 -> fp8 e4m3 (row-major) + c2-scaled fp32 row norms; zero
// partials + block counter.
// n2[row] = c2 * |z_row|^2, c2 = -log2e/sigma (epilogue adds directly).
// ---------------------------------------------------------------------------
__global__ __launch_bounds__(256) void mmd_prep(const float* __restrict__ X,
                                                const float* __restrict__ Y,
                                                const int* __restrict__ sigmap,
                                                unsigned char* __restrict__ Zf8,
                                                float* __restrict__ n2,
                                                float* __restrict__ part,
                                                int* __restrict__ cnt) {
    if (blockIdx.x == 0 && threadIdx.x < 64) part[threadIdx.x] = 0.0f;
    if (blockIdx.x == 0 && threadIdx.x == 64) *cnt = 0;

    const int wave = threadIdx.x >> 6;
    const int lane = threadIdx.x & 63;
    const int row  = blockIdx.x * 4 + wave;          // 0 .. TWO_N-1

    const float* src = (row < N_PTS) ? (X + (size_t)row * DIM)
                                     : (Y + (size_t)(row - N_PTS) * DIM);
    float4 v = ((const float4*)src)[lane];           // 64 lanes x 4 = 256

    float s = v.x * v.x + v.y * v.y + v.z * v.z + v.w * v.w;
#pragma unroll
    for (int off = 32; off; off >>= 1) s += __shfl_down(s, off, 64);
    if (lane == 0) {
        const float c2 = -1.4426950408889634f / (float)(*sigmap);
        n2[row] = c2 * s;
    }

    const int p01 = __builtin_amdgcn_cvt_pk_fp8_f32(v.x, v.y, 0, false);
    const int p23 = __builtin_amdgcn_cvt_pk_fp8_f32(v.z, v.w, 0, false);
    const unsigned int pk = ((unsigned)p01 & 0xffffu) | ((unsigned)p23 << 16);
    *(unsigned int*)(Zf8 + (size_t)row * DIM + (size_t)lane * 4) = pk;
}

// ---------------------------------------------------------------------------
// Main. grid = 1024: p = bid>>4 (row pair {p, 127-p}), cc = bid&15.
// For each owned row r, tiles bc = cc, cc+16, .. <= r; 2 col-slices per tile
// (h=0,1: cols bc*128+h*64..+64, full K=256). 4 waves in 4x1. Per slice:
// [barrier][stage next][16 MFMA 16x16x128 MX-fp8][epilogue]. LDS col =
// 256 B = 16 x 16B slots; slot s of col c holds global chunk s ^ (c&15).
// Tail: hashed-partial atomics + last-block final reduction (fused finish).
// ---------------------------------------------------------------------------
__global__ __launch_bounds__(256, 4) void mmd_main(const unsigned char* __restrict__ Zf8,
                                                   const float* __restrict__ n2,
                                                   const int* __restrict__ sigmap,
                                                   float* __restrict__ part,
                                                   int* __restrict__ cnt,
                                                   float* __restrict__ out) {
    __shared__ char smem_b[32768];   // 2 x 16 KB col-slice buffers
    __shared__ float wsum[4];
    __shared__ int lastFlag;

    const int bid = (int)blockIdx.x;
    const int p   = bid >> 4;        // 0..63
    const int cc  = bid & 15;
    const int r0  = p;               // row tile 0..63
    const int r1  = 127 - p;         // row tile 64..127

    const int nT0 = (cc <= r0) ? (((r0 - cc) >> 4) + 1) : 0;
    const int nT1 = ((r1 - cc) >> 4) + 1;
    const int nS0 = nT0 * 2;
    const int nS  = nS0 + nT1 * 2;

    const int t    = threadIdx.x;
    const int wave = t >> 6;         // 0..3: 32-row group
    const int lane = t & 63;
    const int g    = lane >> 4;      // k-quad
    const int ml   = lane & 15;

    const float m2 = 2.8853900817779268f / (float)(*sigmap);   // 2*log2e/sigma
    const int   SC = 0x7f7f7f7f;     // E8M0 unit scales (2^0)

    // ---- staging invariants: 1024 16B chunks / 256 threads = 4 per thread
    const int gbase = (t >> 4) * 256 + (((t & 15) ^ (t >> 4)) * 16);
    const int lbase = t * 16;

    // ---- bf ds_read bases (col = nt*16 + ml within slice) ----
    int rb0[2], rb1[2];
#pragma unroll
    for (int kc = 0; kc < 2; ++kc) {
        rb0[kc] = ml * 256 + (((kc * 8 + g * 2)     ^ ml) * 16);
        rb1[kc] = ml * 256 + (((kc * 8 + g * 2 + 1) ^ ml) * 16);
    }

    // ---- A-panel registers (reloaded once at row switch) ----
    i32x8 af[2][2];
    float a_i[2][4];
    auto loadA = [&](int rowTile) {
        const int rowBase = rowTile * 128;
#pragma unroll
        for (int mt = 0; mt < 2; ++mt) {
            const unsigned char* rp =
                Zf8 + (size_t)(rowBase + wave * 32 + mt * 16 + ml) * 256 + g * 32;
#pragma unroll
            for (int kc = 0; kc < 2; ++kc) {
                union { i32x4 h[2]; i32x8 v; } u;
                u.h[0] = *(const i32x4*)(rp + kc * 128);
                u.h[1] = *(const i32x4*)(rp + kc * 128 + 16);
                af[mt][kc] = u.v;
            }
        }
#pragma unroll
        for (int mt = 0; mt < 2; ++mt)
#pragma unroll
            for (int rr = 0; rr < 4; ++rr)
                a_i[mt][rr] = n2[rowBase + wave * 32 + mt * 16 + g * 4 + rr];
    };

    const int firstRow = nT0 ? r0 : r1;
    loadA(firstRow);
    int curRow = firstRow;

    const f32x4 zacc = {0.0f, 0.0f, 0.0f, 0.0f};

    // slice s -> (rowTile, bc, h); colBase = bc*128 + h*64
    auto sliceCol = [&](int s, int& rowT, int& bc, int& h) {
        int si;
        if (s < nS0) { rowT = r0; si = s; }
        else         { rowT = r1; si = s - nS0; }
        bc = cc + ((si >> 1) * 16);
        h  = si & 1;
    };

    // ---- prologue: stage slice 0 ----
    {
        int rT, bc, h; sliceCol(0, rT, bc, h);
        const unsigned char* sb = Zf8 + (size_t)(bc * 128 + h * 64) * 256 + gbase;
#pragma unroll
        for (int i = 0; i < 4; ++i)
            __builtin_amdgcn_global_load_lds((const AS1 void*)(sb + i * 4096),
                                             (AS3 void*)(smem_b + i * 4096 + lbase), 16, 0, 0);
    }

    float block_acc = 0.0f;
    int cur = 0;

    for (int s = 0; s < nS; ++s) {
        int rowT, bc, h;
        sliceCol(s, rowT, bc, h);
        if (rowT != curRow) { loadA(rowT); curRow = rowT; }   // once per block
        const int colBase = bc * 128 + h * 64;

        // per-slice multiplicative column factors
        float eb[4];
#pragma unroll
        for (int nt = 0; nt < 4; ++nt)
            eb[nt] = __builtin_amdgcn_exp2f(n2[colBase + nt * 16 + ml]);

        __syncthreads();             // slice s staged in buf cur; cur^1 free

        // ---- stage next slice into the other buffer (overlaps compute) ----
        if (s + 1 < nS) {
            int rTN, bcN, hN;
            sliceCol(s + 1, rTN, bcN, hN);
            const unsigned char* sb =
                Zf8 + (size_t)(bcN * 128 + hN * 64) * 256 + gbase;
            char* dst = smem_b + (cur ^ 1) * 16384;
#pragma unroll
            for (int i = 0; i < 4; ++i)
                __builtin_amdgcn_global_load_lds((const AS1 void*)(sb + i * 4096),
                                                 (AS3 void*)(dst + i * 4096 + lbase), 16, 0, 0);
        }

        // ---- compute: 4 nt x (2 mt x 2 kc) MFMA, full-K per slice ----
        const char* buf = smem_b + cur * 16384;
        f32x4 acc[2][4];
#pragma unroll
        for (int nt = 0; nt < 4; ++nt) {
#pragma unroll
            for (int kc = 0; kc < 2; ++kc) {
                union { i32x4 hh[2]; i32x8 v; } u;
                u.hh[0] = *(const i32x4*)(buf + nt * 4096 + rb0[kc]);
                u.hh[1] = *(const i32x4*)(buf + nt * 4096 + rb1[kc]);
                const i32x8 bf = u.v;
#pragma unroll
                for (int mt = 0; mt < 2; ++mt)
                    acc[mt][nt] = __builtin_amdgcn_mfma_scale_f32_16x16x128_f8f6f4(
                        af[mt][kc], bf, (kc == 0) ? zacc : acc[mt][nt],
                        0, 0, 0, SC, 0, SC);
            }
        }

        // ---- epilogue for this slice ----
        float ts0 = 0.0f, ts1 = 0.0f, ts2 = 0.0f, ts3 = 0.0f;
#pragma unroll
        for (int mt = 0; mt < 2; ++mt)
#pragma unroll
            for (int nt = 0; nt < 4; ++nt) {
                const float e = eb[nt];
                ts0 = fmaf(__builtin_amdgcn_exp2f(fmaf(acc[mt][nt][0], m2, a_i[mt][0])), e, ts0);
                ts1 = fmaf(__builtin_amdgcn_exp2f(fmaf(acc[mt][nt][1], m2, a_i[mt][1])), e, ts1);
                ts2 = fmaf(__builtin_amdgcn_exp2f(fmaf(acc[mt][nt][2], m2, a_i[mt][2])), e, ts2);
                ts3 = fmaf(__builtin_amdgcn_exp2f(fmaf(acc[mt][nt][3], m2, a_i[mt][3])), e, ts3);
            }
        const float tsum = (ts0 + ts1) + (ts2 + ts3);

        const float sgn = ((bc < 64) == (rowT < 64)) ? 1.0f : -1.0f;
        const float w   = (bc == rowT) ? sgn : 2.0f * sgn;   // symmetry weight
        block_acc = fmaf(w, tsum, block_acc);
        cur ^= 1;
    }

    // ---- block reduction + hashed atomic ----
    float s = block_acc;
#pragma unroll
    for (int off = 32; off; off >>= 1) s += __shfl_down(s, off, 64);
    if (lane == 0) wsum[wave] = s;
    __syncthreads();
    if (t == 0) {
        atomicAdd(part + (bid & 63), wsum[0] + wsum[1] + wsum[2] + wsum[3]);
        __threadfence();                               // partial visible
        const int old = atomicAdd(cnt, 1);
        lastFlag = (old == 1023);                      // grid = 1024 blocks
    }
    __syncthreads();

    // ---- fused finish: last block reduces the 64 partials ----
    if (lastFlag && wave == 0) {
        __threadfence();
        float v = __hip_atomic_load(part + lane, __ATOMIC_RELAXED,
                                    __HIP_MEMORY_SCOPE_AGENT);
#pragma unroll
        for (int off = 32; off; off >>= 1) v += __shfl_down(v, off, 64);
        if (lane == 0) out[0] = v * (1.0f / 67108864.0f);
    }
}

// ---------------------------------------------------------------------------
extern "C" void kernel_launch(void* const* d_in, const int* in_sizes, int n_in,
                              void* d_out, int out_size, void* d_ws, size_t ws_size,
                              hipStream_t stream) {
    const float* X      = (const float*)d_in[0];
    const float* Y      = (const float*)d_in[1];
    const int*   sigmap = (const int*)d_in[2];
    float*       out    = (float*)d_out;

    unsigned char* Zf8  = (unsigned char*)d_ws;                       // 4 MB
    float*         n2   = (float*)((char*)d_ws + (size_t)TWO_N * DIM);
    float*         part = n2 + TWO_N;                                 // 64 floats
    int*           cnt  = (int*)(part + 64);                          // 1 int

    mmd_prep<<<TWO_N / 4, 256, 0, stream>>>(X, Y, sigmap, Zf8, n2, part, cnt);
    mmd_main<<<64 * 16, 256, 0, stream>>>(Zf8, n2, sigmap, part, cnt, out);
}

// Round 13
// 114.144 us; speedup vs baseline: 1.8739x; 1.0790x over previous
//
#include <hip/hip_runtime.h>
#include <hip/hip_bf16.h>
#include <stdint.h>
#include <stddef.h>

// MMD via single signed 2N x 2N RBF gram, lower triangle only.
// Round 19 (resubmit; r12 bench was a container-level failure — same
// signature as r3/r4 which later ran fine unchanged; sync structure
// re-audited: uniform barrier count, terminating waits, sound FIFO logic).
// T3/T4+T5 port onto the r15 structure (best measured: 52.4 us).
// Per slice: [eb loads] [ds_read+MFMA w/ s_setprio(1)] [lgkmcnt(0)+s_barrier]
// [issue stage(s+2) into just-freed buffer] [epilogue] [s_waitcnt vmcnt(4)
// (counted, never 0 in steady state) + s_barrier]. Depth-2 prefetch, raw
// barriers, no full drain: m233 showed the 2-phase stage+drain+barrier
// structure is ~72% of critical path; m218 counted-vmcnt was +38-73%.
// 3-launch config (prep/main/finish) = best-measured baseline.

#define N_PTS   8192
#define DIM     256
#define TWO_N   16384

#define AS1 __attribute__((address_space(1)))
#define AS3 __attribute__((address_space(3)))

typedef __attribute__((ext_vector_type(4))) float f32x4;
typedef __attribute__((ext_vector_type(4))) int   i32x4;
typedef __attribute__((ext_vector_type(8))) int   i32x8;

#define WAIT_VM4()  asm volatile("s_waitcnt vmcnt(4)" ::: "memory")
#define WAIT_VM0()  asm volatile("s_waitcnt vmcnt(0)" ::: "memory")
#define WAIT_LGKM() asm volatile("s_waitcnt lgkmcnt(0)" ::: "memory")
#define SCHEDB()    __builtin_amdgcn_sched_barrier(0)
#define BARRIER()   __builtin_amdgcn_s_barrier()

// ---------------------------------------------------------------------------
// Prep: fp32 -> fp8 e4m3 (row-major) + c2-scaled fp32 row norms; zero partials.
// n2[row] = c2 * |z_row|^2, c2 = -log2e/sigma (epilogue adds directly).
// ---------------------------------------------------------------------------
__global__ __launch_bounds__(256) void mmd_prep(const float* __restrict__ X,
                                                const float* __restrict__ Y,
                                                const int* __restrict__ sigmap,
                                                unsigned char* __restrict__ Zf8,
                                                float* __restrict__ n2,
                                                float* __restrict__ part) {
    if (blockIdx.x == 0 && threadIdx.x < 64) part[threadIdx.x] = 0.0f;

    const int wave = threadIdx.x >> 6;
    const int lane = threadIdx.x & 63;
    const int row  = blockIdx.x * 4 + wave;          // 0 .. TWO_N-1

    const float* src = (row < N_PTS) ? (X + (size_t)row * DIM)
                                     : (Y + (size_t)(row - N_PTS) * DIM);
    float4 v = ((const float4*)src)[lane];           // 64 lanes x 4 = 256

    float s = v.x * v.x + v.y * v.y + v.z * v.z + v.w * v.w;
#pragma unroll
    for (int off = 32; off; off >>= 1) s += __shfl_down(s, off, 64);
    if (lane == 0) {
        const float c2 = -1.4426950408889634f / (float)(*sigmap);
        n2[row] = c2 * s;
    }

    const int p01 = __builtin_amdgcn_cvt_pk_fp8_f32(v.x, v.y, 0, false);
    const int p23 = __builtin_amdgcn_cvt_pk_fp8_f32(v.z, v.w, 0, false);
    const unsigned int pk = ((unsigned)p01 & 0xffffu) | ((unsigned)p23 << 16);
    *(unsigned int*)(Zf8 + (size_t)row * DIM + (size_t)lane * 4) = pk;
}

// ---------------------------------------------------------------------------
// Main. grid = 1024: p = bid>>4 (row pair {p, 127-p}), cc = bid&15.
// For each owned row r, tiles bc = cc, cc+16, .. <= r; 2 col-slices per tile
// (h=0,1: cols bc*128+h*64..+64, full K=256). 4 waves in 4x1. LDS col =
// 256 B = 16 x 16B slots; slot s of col c holds global chunk s ^ (c&15).
// Depth-2 staging: slice s+2 issued into the buffer freed by slice s's reads.
// ---------------------------------------------------------------------------
__global__ __launch_bounds__(256, 4) void mmd_main(const unsigned char* __restrict__ Zf8,
                                                   const float* __restrict__ n2,
                                                   const int* __restrict__ sigmap,
                                                   float* __restrict__ part) {
    __shared__ char smem_b[32768];   // 2 x 16 KB col-slice buffers
    __shared__ float wsum[4];

    const int bid = (int)blockIdx.x;
    const int p   = bid >> 4;        // 0..63
    const int cc  = bid & 15;
    const int r0  = p;               // row tile 0..63
    const int r1  = 127 - p;         // row tile 64..127

    const int nT0 = (cc <= r0) ? (((r0 - cc) >> 4) + 1) : 0;
    const int nT1 = ((r1 - cc) >> 4) + 1;
    const int nS0 = nT0 * 2;
    const int nS  = nS0 + nT1 * 2;   // always >= 8

    const int t    = threadIdx.x;
    const int wave = t >> 6;         // 0..3: 32-row group
    const int lane = t & 63;
    const int g    = lane >> 4;      // k-quad
    const int ml   = lane & 15;

    const float m2 = 2.8853900817779268f / (float)(*sigmap);   // 2*log2e/sigma
    const int   SC = 0x7f7f7f7f;     // E8M0 unit scales (2^0)

    // ---- staging invariants: 1024 16B chunks / 256 threads = 4 per thread
    const int gbase = (t >> 4) * 256 + (((t & 15) ^ (t >> 4)) * 16);
    const int lbase = t * 16;

    // ---- bf ds_read bases (col = nt*16 + ml within slice) ----
    int rb0[2], rb1[2];
#pragma unroll
    for (int kc = 0; kc < 2; ++kc) {
        rb0[kc] = ml * 256 + (((kc * 8 + g * 2)     ^ ml) * 16);
        rb1[kc] = ml * 256 + (((kc * 8 + g * 2 + 1) ^ ml) * 16);
    }

    // ---- A-panel registers (reloaded once at row switch) ----
    i32x8 af[2][2];
    float a_i[2][4];
    auto loadA = [&](int rowTile) {
        const int rowBase = rowTile * 128;
#pragma unroll
        for (int mt = 0; mt < 2; ++mt) {
            const unsigned char* rp =
                Zf8 + (size_t)(rowBase + wave * 32 + mt * 16 + ml) * 256 + g * 32;
#pragma unroll
            for (int kc = 0; kc < 2; ++kc) {
                union { i32x4 h[2]; i32x8 v; } u;
                u.h[0] = *(const i32x4*)(rp + kc * 128);
                u.h[1] = *(const i32x4*)(rp + kc * 128 + 16);
                af[mt][kc] = u.v;
            }
        }
#pragma unroll
        for (int mt = 0; mt < 2; ++mt)
#pragma unroll
            for (int rr = 0; rr < 4; ++rr)
                a_i[mt][rr] = n2[rowBase + wave * 32 + mt * 16 + g * 4 + rr];
    };

    // slice s -> (rowTile, bc, h); colBase = bc*128 + h*64
    auto sliceCol = [&](int s, int& rowT, int& bc, int& h) {
        int si;
        if (s < nS0) { rowT = r0; si = s; }
        else         { rowT = r1; si = s - nS0; }
        bc = cc + ((si >> 1) * 16);
        h  = si & 1;
    };

    auto stageTo = [&](char* dstBuf, int s) {
        int rT, bc, h; sliceCol(s, rT, bc, h);
        const unsigned char* sb = Zf8 + (size_t)(bc * 128 + h * 64) * 256 + gbase;
#pragma unroll
        for (int i = 0; i < 4; ++i)
            __builtin_amdgcn_global_load_lds((const AS1 void*)(sb + i * 4096),
                                             (AS3 void*)(dstBuf + i * 4096 + lbase), 16, 0, 0);
    };

    const int firstRow = nT0 ? r0 : r1;
    loadA(firstRow);                 // af/a_i loads are oldest in the FIFO
    int curRow = firstRow;

    const f32x4 zacc = {0.0f, 0.0f, 0.0f, 0.0f};

    // ---- prologue: depth-2 stage, drain slice 0 only ----
    stageTo(smem_b,         0);
    stageTo(smem_b + 16384, 1);
    WAIT_VM4();                      // drains loadA + stage(0); stage(1) in flight
    SCHEDB(); BARRIER(); SCHEDB();

    float block_acc = 0.0f;
    int cur = 0;

    for (int s = 0; s < nS; ++s) {
        int rowT, bc, h;
        sliceCol(s, rowT, bc, h);
        if (rowT != curRow) { loadA(rowT); curRow = rowT; }   // once per block
        const int colBase = bc * 128 + h * 64;

        // eb loads early (older than stage(s+2); exp2 deferred to epilogue)
        float ebl[4];
#pragma unroll
        for (int nt = 0; nt < 4; ++nt)
            ebl[nt] = n2[colBase + nt * 16 + ml];

        // ---- compute: 4 nt x (2 mt x 2 kc) MFMA, setprio around cluster ----
        const char* buf = smem_b + cur * 16384;
        f32x4 acc[2][4];
        __builtin_amdgcn_s_setprio(1);
#pragma unroll
        for (int nt = 0; nt < 4; ++nt) {
#pragma unroll
            for (int kc = 0; kc < 2; ++kc) {
                union { i32x4 hh[2]; i32x8 v; } u;
                u.hh[0] = *(const i32x4*)(buf + nt * 4096 + rb0[kc]);
                u.hh[1] = *(const i32x4*)(buf + nt * 4096 + rb1[kc]);
                const i32x8 bf = u.v;
#pragma unroll
                for (int mt = 0; mt < 2; ++mt)
                    acc[mt][nt] = __builtin_amdgcn_mfma_scale_f32_16x16x128_f8f6f4(
                        af[mt][kc], bf, (kc == 0) ? zacc : acc[mt][nt],
                        0, 0, 0, SC, 0, SC);
            }
        }
        __builtin_amdgcn_s_setprio(0);

        // ---- F1: all waves' reads of buf[cur] retired -> buffer reusable ----
        WAIT_LGKM();
        SCHEDB(); BARRIER(); SCHEDB();

        // ---- issue stage(s+2) into the just-freed buffer ----
        const bool more = (s + 2 < nS);
        if (more) stageTo(smem_b + cur * 16384, s + 2);

        // ---- epilogue (eb exp2 here; its wait retires stage(s+1), not s+2) ----
        float ts0 = 0.0f, ts1 = 0.0f, ts2 = 0.0f, ts3 = 0.0f;
        float eb[4];
#pragma unroll
        for (int nt = 0; nt < 4; ++nt)
            eb[nt] = __builtin_amdgcn_exp2f(ebl[nt]);
#pragma unroll
        for (int mt = 0; mt < 2; ++mt)
#pragma unroll
            for (int nt = 0; nt < 4; ++nt) {
                const float e = eb[nt];
                ts0 = fmaf(__builtin_amdgcn_exp2f(fmaf(acc[mt][nt][0], m2, a_i[mt][0])), e, ts0);
                ts1 = fmaf(__builtin_amdgcn_exp2f(fmaf(acc[mt][nt][1], m2, a_i[mt][1])), e, ts1);
                ts2 = fmaf(__builtin_amdgcn_exp2f(fmaf(acc[mt][nt][2], m2, a_i[mt][2])), e, ts2);
                ts3 = fmaf(__builtin_amdgcn_exp2f(fmaf(acc[mt][nt][3], m2, a_i[mt][3])), e, ts3);
            }
        const float tsum = (ts0 + ts1) + (ts2 + ts3);

        const float sgn = ((bc < 64) == (rowT < 64)) ? 1.0f : -1.0f;
        const float w   = (bc == rowT) ? sgn : 2.0f * sgn;   // symmetry weight
        block_acc = fmaf(w, tsum, block_acc);

        // ---- F2: stage(s+1) complete block-wide; stage(s+2) stays in flight
        if (more) { WAIT_VM4(); } else { WAIT_VM0(); }
        SCHEDB(); BARRIER(); SCHEDB();
        cur ^= 1;
    }

    // ---- block reduction + hashed atomic ----
    float s = block_acc;
#pragma unroll
    for (int off = 32; off; off >>= 1) s += __shfl_down(s, off, 64);
    if (lane == 0) wsum[wave] = s;
    __syncthreads();
    if (t == 0)
        atomicAdd(part + (bid & 63), wsum[0] + wsum[1] + wsum[2] + wsum[3]);
}

// ---------------------------------------------------------------------------
// Finish: reduce 64 partials, scale, write scalar output.
// ---------------------------------------------------------------------------
__global__ __launch_bounds__(64) void mmd_finish(const float* __restrict__ part,
                                                 float* __restrict__ out) {
    const int lane = threadIdx.x & 63;
    float s = part[lane];
#pragma unroll
    for (int off = 32; off; off >>= 1) s += __shfl_down(s, off, 64);
    if (lane == 0) out[0] = s * (1.0f / 67108864.0f);
}

// ---------------------------------------------------------------------------
extern "C" void kernel_launch(void* const* d_in, const int* in_sizes, int n_in,
                              void* d_out, int out_size, void* d_ws, size_t ws_size,
                              hipStream_t stream) {
    const float* X      = (const float*)d_in[0];
    const float* Y      = (const float*)d_in[1];
    const int*   sigmap = (const int*)d_in[2];
    float*       out    = (float*)d_out;

    unsigned char* Zf8  = (unsigned char*)d_ws;                       // 4 MB
    float*         n2   = (float*)((char*)d_ws + (size_t)TWO_N * DIM);
    float*         part = n2 + TWO_N;                                 // 64 floats

    mmd_prep<<<TWO_N / 4, 256, 0, stream>>>(X, Y, sigmap, Zf8, n2, part);
    mmd_main<<<64 * 16, 256, 0, stream>>>(Zf8, n2, sigmap, part);
    mmd_finish<<<1, 64, 0, stream>>>(part, out);
}